// Round 15
// baseline (135.547 us; speedup 1.0000x reference)
//
#include <hip/hip_runtime.h>
#include <hip/hip_bf16.h>
#include <stdint.h>

// Problem constants (from reference)
#define N1 8
#define N2 8
#define PP 1024
#define DD 768
#define PH 32
#define PW 32
#define OH 512
#define OW 512

#define NKT 12        // K tiles of 64
#define IMG_PK 786432 // packed bytes per image = PP*DD

typedef int i32x4 __attribute__((ext_vector_type(4)));

// ---------------- K1: row L2-normalize f32 -> i8 (q = round(127*x/||x||)) --
// Verified R7-R13: final absmax 3.9e-3 vs threshold 1.35e-2.
__global__ __launch_bounds__(256) void nrm_kernel(
    const float* __restrict__ inA, const float* __restrict__ inB,
    char* __restrict__ outA, char* __restrict__ outB) {
  int row = blockIdx.x;
  const float* src;
  char* dst;
  if (row < N1 * PP) {
    src = inA + (size_t)row * DD;
    dst = outA + (size_t)row * DD;
  } else {
    row -= N1 * PP;
    src = inB + (size_t)row * DD;
    dst = outB + (size_t)row * DD;
  }
  const int t = threadIdx.x;
  const float v0 = src[t], v1 = src[t + 256], v2 = src[t + 512];
  float s = v0 * v0 + v1 * v1 + v2 * v2;
#pragma unroll
  for (int m = 32; m; m >>= 1) s += __shfl_xor(s, m, 64);
  __shared__ float red[4];
  const int wave = t >> 6, lane = t & 63;
  if (lane == 0) red[wave] = s;
  __syncthreads();
  const float inv = 127.0f / sqrtf(red[0] + red[1] + red[2] + red[3]);
  dst[t]       = (char)__float2int_rn(v0 * inv);
  dst[t + 256] = (char)__float2int_rn(v1 * inv);
  dst[t + 512] = (char)__float2int_rn(v2 * inv);
}

// ---------------- K1b: repack linear i8 -> fragment-packed i8 -------------
// Packed layout per image: frag unit (blk 0..63, kt 0..11) = 1024 B at
// ((blk*12 + kt)*1024); within it, byte (lane, e) = element
// (row = blk*16 + (lane&15), col = kt*64 + (lane>>4)*16 + e).
// A wave's MFMA operand load becomes ONE contiguous 1-KB read (lane*16).
// Dest writes fully coalesced (16 B/thread contiguous); src reads are
// 16-B gathers served by L2 (12 MB total, one pass).
__global__ __launch_bounds__(256) void repack_kernel(
    const char* __restrict__ fq, const char* __restrict__ gq,
    char* __restrict__ fpk, char* __restrict__ gpk) {
  const int c = blockIdx.x * 256 + threadIdx.x;  // dest 16-B chunk id
  const int half = c / (N1 * IMG_PK / 16);       // 0: fq, 1: gq
  const int cl = c - half * (N1 * IMG_PK / 16);
  const int n = cl / (IMG_PK / 16);
  const int u = cl - n * (IMG_PK / 16);          // chunk within image
  const int fu = u >> 6;                          // frag unit
  const int ln = u & 63;                          // lane slot
  const int blk = fu / NKT, kt = fu - blk * NKT;
  const int row = blk * 16 + (ln & 15);
  const int col = kt * 64 + (ln >> 4) * 16;
  const char* src = (half ? gq : fq) + ((size_t)n * PP + row) * DD + col;
  char* dst = (half ? gpk : fpk) + (size_t)c * 16 - (size_t)half * N1 * IMG_PK;
  *(i32x4*)dst = *(const i32x4*)src;
}

// -------- K2: i8 gram row-max, 256x256 tile, ZERO-LDS, L2 fragment reads ---
// R14: operands come straight from fragment-packed GLOBAL (L2-resident:
// 1.5 MB per pair, XCD-swizzled) as coalesced 1-KB wave loads — the LDS
// pipe (measured ~40 cyc/wave-b128 across R8/R9/R12/R13, 3-4x its ubench
// rate) is bypassed entirely. No __shared__, no barriers, no staging;
// waves are fully independent. 8 waves (2M x 4N), per-wave C = 128x64,
// acc[8][4] i32x4. Per kt: 12 global 1-KB loads + 32 MFMA; unroll 2 lets
// the compiler overlap next-kt loads with current MFMA (no barrier drain).
__global__ __launch_bounds__(512) void grami8_kernel(
    const char* __restrict__ fpk, const char* __restrict__ gpk,
    int* __restrict__ rowmaxI) {
  // XCD swizzle: 1024 wgs, 128 contiguous per XCD (bijective, 1024%8==0).
  const int bid = blockIdx.x;
  const int wg = (bid & 7) * 128 + (bid >> 3);
  const int pair = wg >> 4;                 // 0..63
  const int tile = wg & 15;
  const int fn = pair >> 3, gm = pair & 7;
  const int mt = tile >> 2, nt = tile & 3;  // 4x4 tiles of 256x256
  const int brow = mt * 256, bcol = nt * 256;

  const int t = threadIdx.x;
  const int lane = t & 63, wave = t >> 6;
  const int lr = lane & 15, lk = lane >> 4;
  const int wr = wave >> 2, wc = wave & 3;  // 2M x 4N, per-wave 128x64

  // Per-wave fragment base pointers (blk = 16-row block).
  const char* Af = fpk + (size_t)fn * IMG_PK +
                   ((size_t)(mt * 16 + wr * 8) * NKT) * 1024 + lane * 16;
  const char* Bf = gpk + (size_t)gm * IMG_PK +
                   ((size_t)(nt * 16 + wc * 4) * NKT) * 1024 + lane * 16;

  i32x4 acc[8][4];
#pragma unroll
  for (int i = 0; i < 8; ++i)
#pragma unroll
    for (int j = 0; j < 4; ++j) acc[i][j] = (i32x4){0, 0, 0, 0};

#pragma unroll 2
  for (int kt = 0; kt < NKT; ++kt) {
    i32x4 a[8], b[4];
#pragma unroll
    for (int m = 0; m < 8; ++m)
      a[m] = *(const i32x4*)(Af + ((size_t)m * NKT + kt) * 1024);
#pragma unroll
    for (int n = 0; n < 4; ++n)
      b[n] = *(const i32x4*)(Bf + ((size_t)n * NKT + kt) * 1024);
#pragma unroll
    for (int m = 0; m < 8; ++m)
#pragma unroll
      for (int n = 0; n < 4; ++n)
        acc[m][n] = __builtin_amdgcn_mfma_i32_16x16x64_i8(a[m], b[n],
                                                          acc[m][n], 0, 0, 0);
  }

  // Row-max epilogue (R8-verified). C/D layout: col = lr, row = lk*4 + reg.
  int* rm = rowmaxI + (size_t)(fn * 8 + gm) * PP;
#pragma unroll
  for (int m = 0; m < 8; ++m) {
#pragma unroll
    for (int r = 0; r < 4; ++r) {
      int vv = max(max(acc[m][0][r], acc[m][1][r]),
                   max(acc[m][2][r], acc[m][3][r]));
      vv = max(vv, __shfl_xor(vv, 1, 64));
      vv = max(vv, __shfl_xor(vv, 2, 64));
      vv = max(vv, __shfl_xor(vv, 4, 64));
      vv = max(vv, __shfl_xor(vv, 8, 64));
      if (lr == 0) {
        const int row = brow + wr * 128 + m * 16 + lk * 4 + r;
        atomicMax(&rm[row], vv);
      }
    }
  }
}

// ---------------- K3: rowmax(i32) -> dist -> scores + sp ----------------
__global__ __launch_bounds__(256) void finalize_kernel(
    const int* __restrict__ rowmaxI, float* __restrict__ sp,
    float* __restrict__ scores) {
  const int n = blockIdx.x, t = threadIdx.x;
  const int lane = t & 63, wave = t >> 6;
  __shared__ float red[4];
  __shared__ float maxd[N2];
  float spacc[4] = {0.f, 0.f, 0.f, 0.f};
  for (int m = 0; m < N2; ++m) {
    float lmax = -1e30f;
#pragma unroll
    for (int i = 0; i < 4; ++i) {
      const int p = t + i * 256;
      const float g = (float)rowmaxI[(size_t)(n * N2 + m) * PP + p] *
                      (1.0f / 16129.0f);  // 127^2
      const float d = 0.5f * sqrtf(fmaxf(0.f, 2.f - 2.f * g));
      spacc[i] += d;
      lmax = fmaxf(lmax, d);
    }
#pragma unroll
    for (int msk = 32; msk; msk >>= 1) lmax = fmaxf(lmax, __shfl_xor(lmax, msk, 64));
    if (lane == 0) red[wave] = lmax;
    __syncthreads();
    if (t == 0) maxd[m] = fmaxf(fmaxf(red[0], red[1]), fmaxf(red[2], red[3]));
    __syncthreads();
  }
  if (t == 0) {
    float s = 0.f;
    for (int m = 0; m < N2; ++m) s += maxd[m];
    scores[n] = s * (1.0f / N2);
  }
#pragma unroll
  for (int i = 0; i < 4; ++i)
    sp[(size_t)n * PP + t + i * 256] = spacc[i] * (1.0f / N2);
}

// ---------------- K4: bilinear resize 32x32 -> 512x512 ----------------
__global__ __launch_bounds__(256) void resize_kernel(
    const float* __restrict__ sp, float* __restrict__ out) {
  const int idx = blockIdx.x * 256 + threadIdx.x;
  const int ox = idx & (OW - 1);
  const int oy = (idx >> 9) & (OH - 1);
  const int n = idx >> 18;
  const float sy = (oy + 0.5f) * ((float)PH / OH) - 0.5f;
  const float sx = (ox + 0.5f) * ((float)PW / OW) - 0.5f;
  const float y0f = floorf(sy), x0f = floorf(sx);
  const float wy = sy - y0f, wx = sx - x0f;
  int y0 = (int)y0f, x0 = (int)x0f;
  int y1 = y0 + 1, x1 = x0 + 1;
  y0 = min(max(y0, 0), PH - 1);
  y1 = min(max(y1, 0), PH - 1);
  x0 = min(max(x0, 0), PW - 1);
  x1 = min(max(x1, 0), PW - 1);
  const float* s = sp + (size_t)n * PP;
  const float v00 = s[y0 * PW + x0], v01 = s[y0 * PW + x1];
  const float v10 = s[y1 * PW + x0], v11 = s[y1 * PW + x1];
  const float top = v00 * (1.f - wx) + v01 * wx;
  const float bot = v10 * (1.f - wx) + v11 * wx;
  out[idx] = top * (1.f - wy) + bot * wy;
}

extern "C" void kernel_launch(void* const* d_in, const int* in_sizes, int n_in,
                              void* d_out, int out_size, void* d_ws, size_t ws_size,
                              hipStream_t stream) {
  const float* feats = (const float*)d_in[0];
  const float* nfeats = (const float*)d_in[1];
  float* out = (float*)d_out;

  char* ws = (char*)d_ws;
  const size_t FQ_BYTES = (size_t)N1 * PP * DD;  // 6,291,456
  char* fq = ws;
  char* gq = ws + FQ_BYTES;
  char* fpk = ws + 2 * FQ_BYTES;
  char* gpk = ws + 3 * FQ_BYTES;
  int* rowmaxI = (int*)(ws + 4 * FQ_BYTES);
  float* sp = (float*)(ws + 4 * FQ_BYTES + (size_t)N1 * N2 * PP * 4);

  // rowmax sentinel: 0x80808080 = -2139062144 < -768*127^2 (min possible dot)
  hipMemsetAsync(rowmaxI, 0x80, (size_t)N1 * N2 * PP * 4, stream);

  nrm_kernel<<<(N1 + N2) * PP, 256, 0, stream>>>(feats, nfeats, fq, gq);
  repack_kernel<<<(2 * N1 * IMG_PK / 16) / 256, 256, 0, stream>>>(fq, gq, fpk, gpk);

  grami8_kernel<<<1024, 512, 0, stream>>>(fpk, gpk, rowmaxI);

  finalize_kernel<<<N1, 256, 0, stream>>>(rowmaxI, sp, out);
  resize_kernel<<<(N1 * OH * OW) / 256, 256, 0, stream>>>(sp, out + 8);
}